// Round 4
// baseline (671.805 us; speedup 1.0000x reference)
//
#include <hip/hip_runtime.h>
#include <math.h>

typedef _Float16 f16;
typedef _Float16 f16x4 __attribute__((ext_vector_type(4)));
typedef _Float16 f16x8 __attribute__((ext_vector_type(8)));
typedef float f32x4 __attribute__((ext_vector_type(4)));

#define K_HID 2048
#define N_SEQ 4096
#define N_BATCH 2
#define M_ROWS 8192   // B*S

// async global->LDS, 16B per lane. LDS dest must be WAVE-UNIFORM base;
// HW writes lane i at base + i*16 (lane-contiguous). Global src is per-lane.
__device__ __forceinline__ void gl2lds16(const f16* g, f16* l) {
  auto gp = (const __attribute__((address_space(1))) unsigned*)(unsigned long long)(uintptr_t)g;
  auto lp = (__attribute__((address_space(3))) unsigned*)(unsigned)(uintptr_t)l;
  __builtin_amdgcn_global_load_lds(gp, lp, 16, 0, 0);
}

// ---------------- f32 -> f16 conversion (8 elems/thread) ----------------
__global__ __launch_bounds__(256) void cvt_f32_to_f16(const float* __restrict__ x,
                                                      f16* __restrict__ y, int n) {
  int i = (blockIdx.x * 256 + threadIdx.x) * 8;
  if (i >= n) return;
  float4 a = *(const float4*)(x + i);
  float4 b = *(const float4*)(x + i + 4);
  f16x8 o;
  o[0] = (f16)a.x; o[1] = (f16)a.y; o[2] = (f16)a.z; o[3] = (f16)a.w;
  o[4] = (f16)b.x; o[5] = (f16)b.y; o[6] = (f16)b.z; o[7] = (f16)b.w;
  *(f16x8*)(y + i) = o;
}

// -------- weight transpose+convert: W[K][N] f32 -> Wt[N][K] f16 ----------
__global__ __launch_bounds__(256) void transpose_cvt(const float* __restrict__ W0,
                                                     const float* __restrict__ W1,
                                                     const float* __restrict__ W2,
                                                     const float* __restrict__ W3,
                                                     f16* __restrict__ WT) {
  const float* W = (blockIdx.z == 0) ? W0 : (blockIdx.z == 1) ? W1
                 : (blockIdx.z == 2) ? W2 : W3;
  f16* Wt = WT + (size_t)blockIdx.z * K_HID * K_HID;
  __shared__ float tile[32][33];
  int bx = blockIdx.x * 32;   // n base
  int by = blockIdx.y * 32;   // k base
  int x = threadIdx.x & 31;
  int y = threadIdx.x >> 5;   // 0..7
  for (int i = 0; i < 32; i += 8)
    tile[y + i][x] = W[(size_t)(by + y + i) * K_HID + bx + x];
  __syncthreads();
  for (int i = 0; i < 32; i += 8)
    Wt[(size_t)(bx + y + i) * K_HID + by + x] = (f16)tile[x][y + i];
}

// -------- V transpose: V[b][s][h*64+d] f16 -> Vt[(b*32+h)*64+d][s] f16 ----
// Done at f32-pair granularity with an intra-pair fixup (classic tiled
// transpose; all LDS ops vectorized or 2-way-conflict-free).
__global__ __launch_bounds__(256) void v_transpose(const f16* __restrict__ V,
                                                   f16* __restrict__ Vt) {
  __shared__ float tile[64][33];   // [token][dpair]
  int tb = blockIdx.x;             // 64-token tile
  int bh = blockIdx.y;             // b*32+h
  int b = bh >> 5, h = bh & 31;
  const float* src = (const float*)(V + ((size_t)b * N_SEQ) * K_HID + h * 64);
  for (int i = threadIdx.x; i < 2048; i += 256) {
    int tok = i >> 5, dp = i & 31;
    tile[tok][dp] = src[(size_t)(tb * 64 + tok) * (K_HID / 2) + dp];
  }
  __syncthreads();
  float* dst = (float*)Vt + (size_t)bh * 64 * (N_SEQ / 2) + tb * 32;
  for (int i = threadIdx.x; i < 1024; i += 256) {
    int dp = i >> 5, tp = i & 31;
    unsigned x0 = __float_as_uint(tile[tp * 2][dp]);
    unsigned x1 = __float_as_uint(tile[tp * 2 + 1][dp]);
    unsigned w0 = (x0 & 0xFFFFu) | (x1 << 16);
    unsigned w1 = (x0 >> 16) | (x1 & 0xFFFF0000u);
    dst[(size_t)(dp * 2) * (N_SEQ / 2) + tp] = __uint_as_float(w0);
    dst[(size_t)(dp * 2 + 1) * (N_SEQ / 2) + tp] = __uint_as_float(w1);
  }
}

// ---------------- GEMM: C[M][N] = A[M][K] * Bt[N][K]^T ----------------
// 128x128 tile, BK=32, 256 threads, global_load_lds width=16 staging,
// XOR chunk swizzle (conflict-free, verified 0 SQ_LDS_BANK_CONFLICT in R3).
template <typename OutT>
__global__ __launch_bounds__(256) void gemm_bt(const f16* __restrict__ A,
                                               const f16* __restrict__ BtBase,
                                               OutT* __restrict__ CBase,
                                               int M, int N, int Kd,
                                               size_t bzStride, size_t czStride) {
  const f16* Bt = BtBase + bzStride * blockIdx.z;
  OutT* C = CBase + czStride * blockIdx.z;
  __shared__ f16 sA[128 * 32];
  __shared__ f16 sB[128 * 32];
  int tid = threadIdx.x;
  int lane = tid & 63, wave = tid >> 6;
  int quad = lane >> 4, l16 = lane & 15;
  int mBase = blockIdx.y * 128, nBase = blockIdx.x * 128;
  int wm = (wave >> 1) * 64, wn = (wave & 1) * 64;

  f32x4 acc[4][4];
#pragma unroll
  for (int mi = 0; mi < 4; mi++)
#pragma unroll
    for (int ni = 0; ni < 4; ni++) acc[mi][ni] = (f32x4){0.f, 0.f, 0.f, 0.f};

  int rL = lane >> 2;                              // 0..15
  int cSw = ((lane & 3) ^ ((lane >> 3) & 3)) * 8;  // swizzled 8-f16 chunk
  const f16* Ap0 = A + (size_t)(mBase + wave * 32 + rL) * Kd + cSw;
  const f16* Ap1 = Ap0 + (size_t)16 * Kd;
  const f16* Bp0 = Bt + (size_t)(nBase + wave * 32 + rL) * Kd + cSw;
  const f16* Bp1 = Bp0 + (size_t)16 * Kd;
  f16* lA0 = &sA[(wave * 32) * 32];
  f16* lA1 = &sA[(wave * 32 + 16) * 32];
  f16* lB0 = &sB[(wave * 32) * 32];
  f16* lB1 = &sB[(wave * 32 + 16) * 32];

  int rdOff = (quad ^ ((l16 >> 1) & 3)) * 8;

  for (int k0 = 0; k0 < Kd; k0 += 32) {
    gl2lds16(Ap0 + k0, lA0);
    gl2lds16(Ap1 + k0, lA1);
    gl2lds16(Bp0 + k0, lB0);
    gl2lds16(Bp1 + k0, lB1);
    __syncthreads();
    f16x8 af[4], bf[4];
#pragma unroll
    for (int mi = 0; mi < 4; mi++)
      af[mi] = *(const f16x8*)&sA[(wm + mi * 16 + l16) * 32 + rdOff];
#pragma unroll
    for (int ni = 0; ni < 4; ni++)
      bf[ni] = *(const f16x8*)&sB[(wn + ni * 16 + l16) * 32 + rdOff];
#pragma unroll
    for (int mi = 0; mi < 4; mi++)
#pragma unroll
      for (int ni = 0; ni < 4; ni++)
        acc[mi][ni] = __builtin_amdgcn_mfma_f32_16x16x32_f16(af[mi], bf[ni], acc[mi][ni], 0, 0, 0);
    __syncthreads();
  }

#pragma unroll
  for (int mi = 0; mi < 4; mi++) {
    int row = mBase + wm + mi * 16 + quad * 4;
#pragma unroll
    for (int ni = 0; ni < 4; ni++) {
      int col = nBase + wn + ni * 16 + l16;
      OutT* Cp = C + (size_t)row * N + col;
#pragma unroll
      for (int r = 0; r < 4; r++) Cp[(size_t)r * N] = (OutT)acc[mi][ni][r];
    }
  }
}

// ---------------- sliding-tile flash attention, v2 ----------------
// S^T / O^T orientation: mfma(kf,qf) gives S^T (rows=key, cols=q=l16) so the
// softmax stats live at q=l16 and P writes are b64; mfma(vf,pf) gives O^T
// (rows=d, cols=q=l16) so alpha rescale needs no cross-lane moves and the
// final store packs 4 consecutive d. All staging via global_load_lds with
// XOR chunk swizzle (V pre-transposed by v_transpose). sP overlays dead sQ.
__global__ __launch_bounds__(256) void attn_kernel(const f16* __restrict__ Q,
                                                   const f16* __restrict__ Kg,
                                                   const f16* __restrict__ Vt,
                                                   f16* __restrict__ O) {
  __shared__ f16 smem[128 * 64 + 64 * 64 + 64 * 64];   // 32 KB
  f16* sQP = smem;                 // sQ (then reused as sP after qf load)
  f16* sK = smem + 128 * 64;
  f16* sVt = sK + 64 * 64;

  int t = blockIdx.x, h = blockIdx.y, b = blockIdx.z;
  int nth_i = t >> 2, ntw_i = t & 3;    // Ht=8, Wt=4
  int tid = threadIdx.x;
  int lane = tid & 63, wave = tid >> 6;
  int quad = lane >> 4, l16 = lane & 15;
  const size_t bstride = (size_t)N_SEQ * K_HID;
  const f16* Qb = Q + (size_t)b * bstride + h * 64;
  const f16* Kb = Kg + (size_t)b * bstride + h * 64;
  const f16* Vtb = Vt + (size_t)(b * 32 + h) * 64 * N_SEQ;   // rows d, stride S

  const float SC2 = 0.18033688f;   // (1/sqrt(64)) * log2(e)

  int lr = lane >> 3;        // row-within-8 for gl2lds
  int csw = (lane & 7) ^ lr; // swizzled chunk to fetch (stored pos = lane&7)

  // stage Q tile [128 x 64]: 16 gl2lds calls, wave does 4
#pragma unroll
  for (int gi = 0; gi < 4; gi++) {
    int g = wave * 4 + gi;
    int t0 = (nth_i * 8 + (g >> 1)) * 64 + ntw_i * 16 + (g & 1) * 8 + lr;
    gl2lds16(Qb + (size_t)t0 * K_HID + csw * 8, &sQP[g * 8 * 64]);
  }
  __syncthreads();

  f16x8 qf[2][2];   // resident for all chunks
#pragma unroll
  for (int qs = 0; qs < 2; qs++) {
    int qrow = wave * 32 + qs * 16 + l16;
#pragma unroll
    for (int kk = 0; kk < 2; kk++)
      qf[qs][kk] = *(const f16x8*)&sQP[qrow * 64 + (((kk * 4 + quad) ^ (qrow & 7)) * 8)];
  }

  f32x4 oacc[2][4];   // O^T: [qs][dt], rows d=quad*4+r+16dt, col q=qs*16+l16
#pragma unroll
  for (int qs = 0; qs < 2; qs++)
#pragma unroll
    for (int dt = 0; dt < 4; dt++) oacc[qs][dt] = (f32x4){0.f, 0.f, 0.f, 0.f};
  float mrow[2] = {-1e30f, -1e30f}, lrow[2] = {0.f, 0.f};

  int cr = min(max(nth_i, 1), 7);   // clamped window center (tile units)
  int cc = min(max(ntw_i, 1), 3);

  for (int c = 0; c < 8; c++) {
    int kt = c >> 1, half = c & 1;
    int ti = cr - 1 + (kt >> 1), tj = cc - 1 + (kt & 1);
    // stage K [64 keys x 64 d] and Vt [64 d x 64 keys], 8+8 gl2lds calls
#pragma unroll
    for (int gi = 0; gi < 2; gi++) {
      int g = wave * 2 + gi;
      int kr0 = half * 64 + g * 8;
      int tK = (ti * 8 + (kr0 >> 4)) * 64 + tj * 16 + (kr0 & 15) + lr;
      gl2lds16(Kb + (size_t)tK * K_HID + csw * 8, &sK[g * 8 * 64]);
      int kr2 = half * 64 + csw * 8;
      int tV = (ti * 8 + (kr2 >> 4)) * 64 + tj * 16 + (kr2 & 15);
      gl2lds16(Vtb + (size_t)(g * 8 + lr) * N_SEQ + tV, &sVt[g * 8 * 64]);
    }
    __syncthreads();

    // S^T = K Q^T: rows=key (quad*4+r+16ks), cols=q (l16+16qs)
    f32x4 st[4][2];
#pragma unroll
    for (int ks = 0; ks < 4; ks++)
#pragma unroll
      for (int qs = 0; qs < 2; qs++) st[ks][qs] = (f32x4){0.f, 0.f, 0.f, 0.f};
#pragma unroll
    for (int ks = 0; ks < 4; ks++) {
      int krow = ks * 16 + l16;
      f16x8 kf0 = *(const f16x8*)&sK[krow * 64 + ((quad ^ (krow & 7)) * 8)];
      f16x8 kf1 = *(const f16x8*)&sK[krow * 64 + (((4 + quad) ^ (krow & 7)) * 8)];
#pragma unroll
      for (int qs = 0; qs < 2; qs++) {
        st[ks][qs] = __builtin_amdgcn_mfma_f32_16x16x32_f16(kf0, qf[qs][0], st[ks][qs], 0, 0, 0);
        st[ks][qs] = __builtin_amdgcn_mfma_f32_16x16x32_f16(kf1, qf[qs][1], st[ks][qs], 0, 0, 0);
      }
    }

    // online softmax: lane owns q=l16 (+16qs); 16 S values local; 2 shuffles
#pragma unroll
    for (int qs = 0; qs < 2; qs++) {
      int qrow = wave * 32 + qs * 16 + l16;
      float mx = -1e30f;
#pragma unroll
      for (int ks = 0; ks < 4; ks++)
#pragma unroll
        for (int r = 0; r < 4; r++) mx = fmaxf(mx, st[ks][qs][r]);
      mx = fmaxf(mx, __shfl_xor(mx, 16, 64));
      mx = fmaxf(mx, __shfl_xor(mx, 32, 64));
      mx *= SC2;
      float mnew = fmaxf(mrow[qs], mx);
      float alpha = exp2f(mrow[qs] - mnew);
      mrow[qs] = mnew;
      lrow[qs] *= alpha;
#pragma unroll
      for (int dt = 0; dt < 4; dt++) oacc[qs][dt] *= alpha;
      float psum = 0.f;
#pragma unroll
      for (int ks = 0; ks < 4; ks++) {
        f16x4 pv;
#pragma unroll
        for (int r = 0; r < 4; r++) {
          float p = exp2f(st[ks][qs][r] * SC2 - mnew);
          psum += p;
          pv[r] = (f16)p;
        }
        // P[q][key]: keys quad*4..+3 at 16ks; chunk-swizzled stride-64 layout
        *(f16x4*)&sQP[qrow * 64 + (((ks * 2 + (quad >> 1)) ^ (qrow & 7)) * 8 + (quad & 1) * 4)] = pv;
      }
      lrow[qs] += psum;
    }
    // sP is wave-local (each wave reads only its own q rows): no barrier

    // O^T += Vt P^T : mfma(vf, pf) -> rows=d, cols=q
#pragma unroll
    for (int kk = 0; kk < 2; kk++) {
      f16x8 pf[2];
#pragma unroll
      for (int qs = 0; qs < 2; qs++) {
        int qrow = wave * 32 + qs * 16 + l16;
        pf[qs] = *(const f16x8*)&sQP[qrow * 64 + (((kk * 4 + quad) ^ (qrow & 7)) * 8)];
      }
#pragma unroll
      for (int dt = 0; dt < 4; dt++) {
        int drow = dt * 16 + l16;
        f16x8 vf = *(const f16x8*)&sVt[drow * 64 + (((kk * 4 + quad) ^ (drow & 7)) * 8)];
#pragma unroll
        for (int qs = 0; qs < 2; qs++)
          oacc[qs][dt] = __builtin_amdgcn_mfma_f32_16x16x32_f16(vf, pf[qs], oacc[qs][dt], 0, 0, 0);
      }
    }
    __syncthreads();
  }

  // finalize: l reduce over quads, divide, pack 4 consecutive d -> b64 store
  f16* Ob = O + (size_t)b * bstride + h * 64;
#pragma unroll
  for (int qs = 0; qs < 2; qs++) {
    float l = lrow[qs];
    l += __shfl_xor(l, 16, 64);
    l += __shfl_xor(l, 32, 64);
    float inv = 1.0f / l;
    int q = wave * 32 + qs * 16 + l16;
    int tok = (nth_i * 8 + (q >> 4)) * 64 + ntw_i * 16 + (q & 15);
    f16* dst = Ob + (size_t)tok * K_HID;
#pragma unroll
    for (int dt = 0; dt < 4; dt++) {
      f16x4 o4;
#pragma unroll
      for (int r = 0; r < 4; r++) o4[r] = (f16)(oacc[qs][dt][r] * inv);
      *(f16x4*)&dst[dt * 16 + quad * 4] = o4;
    }
  }
}

extern "C" void kernel_launch(void* const* d_in, const int* in_sizes, int n_in,
                              void* d_out, int out_size, void* d_ws, size_t ws_size,
                              hipStream_t stream) {
  const float* hs = (const float*)d_in[0];
  const float* Wq = (const float*)d_in[1];
  const float* Wk = (const float*)d_in[2];
  const float* Wv = (const float*)d_in[3];
  const float* Wo = (const float*)d_in[4];
  float* out = (float*)d_out;

  char* ws = (char*)d_ws;
  const size_t WELEM = (size_t)K_HID * K_HID;      // 4,194,304
  const size_t XELEM = (size_t)M_ROWS * K_HID;     // 16,777,216
  f16* WT = (f16*)ws;  ws += 4 * WELEM * sizeof(f16);  // WqT,WkT,WvT,WoT
  f16* Xh = (f16*)ws;  ws += XELEM * sizeof(f16);
  f16* Qb = (f16*)ws;  ws += XELEM * sizeof(f16);      // Q,K,V contiguous
  f16* Kb = (f16*)ws;  ws += XELEM * sizeof(f16);
  f16* Vb = (f16*)ws;  ws += XELEM * sizeof(f16);
  f16* Ob = (f16*)ws;  ws += XELEM * sizeof(f16);
  f16* VtT = (f16*)ws; ws += XELEM * sizeof(f16);      // V transposed per (b,h)

  cvt_f32_to_f16<<<(int)(XELEM / (256 * 8)), 256, 0, stream>>>(hs, Xh, (int)XELEM);
  transpose_cvt<<<dim3(64, 64, 4), 256, 0, stream>>>(Wq, Wk, Wv, Wo, WT);
  gemm_bt<f16><<<dim3(16, 64, 3), 256, 0, stream>>>(Xh, WT, Qb, M_ROWS, K_HID, K_HID,
                                                    WELEM, XELEM);
  v_transpose<<<dim3(64, 64), 256, 0, stream>>>(Vb, VtT);
  attn_kernel<<<dim3(32, 32, 2), 256, 0, stream>>>(Qb, Kb, VtT, Ob);
  gemm_bt<float><<<dim3(16, 64, 1), 256, 0, stream>>>(Ob, WT + 3 * WELEM, out,
                                                      M_ROWS, K_HID, K_HID, 0, 0);
}